// Round 10
// baseline (1749.471 us; speedup 1.0000x reference)
//
#include <hip/hip_runtime.h>

typedef _Float16 half8 __attribute__((ext_vector_type(8)));
typedef float floatx4 __attribute__((ext_vector_type(4)));

#define B_   8
#define N_   4096
#define S_   2048
#define K_   64
#define CIN  64
#define HID_ 128
#define Q_   (B_*S_)
#define NCONS 248            // consumer blocks in k_front (blocks 8..255)

// ---------------- ws layout (bytes) ----------------
#define WS_STATS 0u          // 512 u64 (sum0,sq0,sum1,sq1) = 4096
#define WS_CNTT  4096u       // int, padded
#define WS_W0T   4224u       // 128*96 f16 = 24576
#define WS_W1T   28800u      // 128*128 f16 = 32768
#define WS_W2T   61568u      // 32768
#define WS_SC0   94336u      // 128 f32
#define WS_SH0   94848u
#define WS_SC1   95360u
#define WS_SH1   95872u
#define WS_CNT   96384u      // 16384 int = 65536
#define WS_NBR   161920u     // 16384*64 u16 = 2097152
#define WS_PROG  2259072u    // 8 int flags (+pad)
#define WS_H0    2260992u    // optional h0: 16384*64*128 f16 = 268435456
#define H0_BYTES 268435456ULL

// ---------------------------------------------------------------- prep
__global__ __launch_bounds__(256) void k_prep(const float* __restrict__ W0,
        const float* __restrict__ W1, const float* __restrict__ W2,
        _Float16* __restrict__ w0t, _Float16* __restrict__ w1t, _Float16* __restrict__ w2t,
        unsigned long long* __restrict__ stats, int* __restrict__ cntT, int* __restrict__ prog) {
    int t = blockIdx.x * 256 + threadIdx.x;
    if (t < 128 * 96) {                       // W0T[c][k], k padded 67->96 with 0
        int c = t / 96, k = t - c * 96;
        w0t[t] = (k < 67) ? (_Float16)W0[k * 128 + c] : (_Float16)0.f;
    } else if (t < 128 * 96 + 16384) {        // W1T[c][k]
        int u = t - 128 * 96; int c = u >> 7, k = u & 127;
        w1t[u] = (_Float16)W1[k * 128 + c];
    } else if (t < 128 * 96 + 32768) {        // W2T[c][k]
        int u = t - 128 * 96 - 16384; int c = u >> 7, k = u & 127;
        w2t[u] = (_Float16)W2[k * 128 + c];
    }
    if (t < 512) stats[t] = 0ULL;
    if (t < 8) prog[t] = 0;
    if (t == 0) *cntT = 0;
}

// ---------------------------------------------------------------- front: FPS producers + nbr/mlp0 consumers
// Blocks 0..7: r3-exact FPS loop (measured floor — r4/r5/r7 all regressed)
// + batched flush every 64 iters (agent-scope stores -> barrier drain ->
// release flag). Blocks 8..255: per-query consumers (spin on prog[b], then
// nbr exact-rank-select + gather + GEMM0 + stats0; optionally store h0 f16).
// r10: LDS padded to 84KB -> hard 1 block/CU -> producers never share a CU
// with a consumer (r9 packed 2/CU and stole producer issue slots).
template<int CTRL>
__device__ inline unsigned long long dpp64(unsigned long long v) {
    int lo = (int)(unsigned)v, hi = (int)(unsigned)(v >> 32);
    int nlo = __builtin_amdgcn_update_dpp(lo, lo, CTRL, 0xF, 0xF, false);
    int nhi = __builtin_amdgcn_update_dpp(hi, hi, CTRL, 0xF, 0xF, false);
    return ((unsigned long long)(unsigned)nhi << 32) | (unsigned long long)(unsigned)nlo;
}
__device__ inline unsigned long long u64max(unsigned long long a, unsigned long long b) {
    return (b > a) ? b : a;
}

__global__ __launch_bounds__(256) void k_front(const float* __restrict__ pos,
        const float* __restrict__ x, const _Float16* __restrict__ w0t,
        const float* __restrict__ b0, float* outCtr, float* __restrict__ outBatch,
        unsigned short* __restrict__ nbrG, int* __restrict__ cnt, int* __restrict__ cntT,
        unsigned long long* __restrict__ statsOut, int* prog,
        _Float16* __restrict__ h0, int doH0) {
    __shared__ __align__(16) char uLDS[84480];   // >81920 -> 1 block/CU guaranteed
    int tid = threadIdx.x;

    if (blockIdx.x < 8) {
        // ================= PRODUCER (r3 FPS + batched flush) =================
        float4* sP4 = (float4*)uLDS;                               // 64 KB
        unsigned long long* red = (unsigned long long*)(uLDS + 65536);
        unsigned short* sSeq = (unsigned short*)(uLDS + 65600);    // 4 KB
        int b = blockIdx.x;
        const float* P = pos + (size_t)b * N_ * 3;

        float px[16], py[16], pz[16], md[16];
        {
            const float4* vp = (const float4*)(P + tid * 48);
            float a[48];
            #pragma unroll
            for (int v = 0; v < 12; v++) {
                float4 t4 = vp[v];
                a[v*4] = t4.x; a[v*4+1] = t4.y; a[v*4+2] = t4.z; a[v*4+3] = t4.w;
            }
            #pragma unroll
            for (int j = 0; j < 16; j++) {
                px[j] = a[3*j]; py[j] = a[3*j+1]; pz[j] = a[3*j+2];
                md[j] = __builtin_inff();
                sP4[tid * 16 + j] = make_float4(px[j], py[j], pz[j], 0.f);
            }
        }
        __syncthreads();

        int last = 0;
        for (int i = 0; i < S_; i++) {
            float4 cc = sP4[last];                       // broadcast ds_read_b128
            if (tid == (i & 255)) sSeq[i] = (unsigned short)last;
            unsigned long long best;
            {
                #pragma clang fp contract(off)
                float bv = -1.f; unsigned bi = 0;
                #pragma unroll
                for (int j = 0; j < 16; j++) {
                    float dx = px[j] - cc.x, dy = py[j] - cc.y, dz = pz[j] - cc.z;
                    float d = (dx * dx + dy * dy) + dz * dz;   // numpy order, no fma
                    float m = fminf(md[j], d); md[j] = m;
                    if (m > bv) { bv = m; bi = (unsigned)j; } // strict > => first index
                }
                best = ((unsigned long long)__float_as_uint(bv) << 32)
                     | (unsigned long long)(0xFFFFu - (unsigned)(tid * 16) - bi);
            }
            best = u64max(best, dpp64<0x111>(best));   // row_shr:1
            best = u64max(best, dpp64<0x112>(best));   // row_shr:2
            best = u64max(best, dpp64<0x114>(best));   // row_shr:4
            best = u64max(best, dpp64<0x118>(best));   // row_shr:8
            best = u64max(best, dpp64<0x142>(best));   // row_bcast:15
            best = u64max(best, dpp64<0x143>(best));   // row_bcast:31 -> lane63 = wave max
            if ((tid & 63) == 63) red[(i & 1) * 4 + (tid >> 6)] = best;
            __syncthreads();   // double-buffered red: one barrier/iter race-free
            ulonglong2 ra = *(const ulonglong2*)&red[(i & 1) * 4];
            ulonglong2 rb = *(const ulonglong2*)&red[(i & 1) * 4 + 2];
            unsigned long long g = u64max(u64max(ra.x, ra.y), u64max(rb.x, rb.y));
            last = (int)(0xFFFFu - (unsigned)(g & 0xFFFFu));
            if ((i & 63) == 63) {   // flush 64 centroids (off the per-iter path)
                if (tid < 64) {
                    int ii = i - 63 + tid;
                    float4 c = sP4[sSeq[ii]];
                    size_t o = (size_t)b * S_ + ii;
                    __hip_atomic_store(&outCtr[o*3],   c.x, __ATOMIC_RELAXED, __HIP_MEMORY_SCOPE_AGENT);
                    __hip_atomic_store(&outCtr[o*3+1], c.y, __ATOMIC_RELAXED, __HIP_MEMORY_SCOPE_AGENT);
                    __hip_atomic_store(&outCtr[o*3+2], c.z, __ATOMIC_RELAXED, __HIP_MEMORY_SCOPE_AGENT);
                    outBatch[o] = (float)b;
                }
                __syncthreads();   // implicit vmcnt(0): stores at coherence point
                if (tid == 0)
                    __hip_atomic_store(&prog[b], i + 1, __ATOMIC_RELEASE, __HIP_MEMORY_SCOPE_AGENT);
            }
        }
    } else {
        // ================= CONSUMER (nbr + mlp stage0 per query) =================
        float* cD = (float*)uLDS;                          // 4 KB
        unsigned short* cI = (unsigned short*)(uLDS + 4096);
        unsigned short* sNbr = (unsigned short*)(uLDS + 6144);
        float* sB0v = (float*)(uLDS + 6272);
        float* sCtr = (float*)(uLDS + 6784);
        int* cN = (int*)(uLDS + 6800);
        _Float16* sBuf = (_Float16*)(uLDS + 6912);         // 64*104 f16 = 13312
        _Float16* sOut = (_Float16*)(uLDS + 20224);        // 64*128 f16 = 16384

        int wid = tid >> 6, lane = tid & 63;
        int lr = lane & 15, lq = lane >> 4;
        int colbase = 32 * wid + lr;
        half8 w0f[3][2];
        #pragma unroll
        for (int ks = 0; ks < 3; ks++)
            #pragma unroll
            for (int nt = 0; nt < 2; nt++)
                w0f[ks][nt] = *(const half8*)(w0t + (colbase + 16*nt) * 96 + ks * 32 + lq * 8);
        if (tid < 128) sB0v[tid] = b0[tid];
        float runS1[2] = {0.f, 0.f}, runS2[2] = {0.f, 0.f};

        for (int k = (int)blockIdx.x - 8; k < Q_; k += NCONS) {
            int i = k >> 3, b = k & 7;
            int q = (b << 11) + i;
            if (tid == 0) {
                while (__hip_atomic_load(&prog[b], __ATOMIC_ACQUIRE, __HIP_MEMORY_SCOPE_AGENT) <= i)
                    __builtin_amdgcn_s_sleep(32);
                sCtr[0] = __hip_atomic_load(&outCtr[(size_t)q*3],   __ATOMIC_RELAXED, __HIP_MEMORY_SCOPE_AGENT);
                sCtr[1] = __hip_atomic_load(&outCtr[(size_t)q*3+1], __ATOMIC_RELAXED, __HIP_MEMORY_SCOPE_AGENT);
                sCtr[2] = __hip_atomic_load(&outCtr[(size_t)q*3+2], __ATOMIC_RELAXED, __HIP_MEMORY_SCOPE_AGENT);
                *cN = 0;
            }
            __syncthreads();   // B1
            float cx = sCtr[0], cy = sCtr[1], cz = sCtr[2];
            const float* P = pos + (size_t)b * N_ * 3;
            float a[48];
            {
                const float4* vp = (const float4*)(P + (size_t)tid * 48);
                #pragma unroll
                for (int v = 0; v < 12; v++) {
                    float4 t4 = vp[v];
                    a[v*4] = t4.x; a[v*4+1] = t4.y; a[v*4+2] = t4.z; a[v*4+3] = t4.w;
                }
            }
            unsigned msk = 0;
            float d2a[16];
            {
                #pragma clang fp contract(off)
                #pragma unroll
                for (int j = 0; j < 16; j++) {
                    float dx = cx - a[3*j], dy = cy - a[3*j+1], dz = cz - a[3*j+2];
                    float d2 = (dx * dx + dy * dy) + dz * dz;
                    d2a[j] = d2;
                    if (d2 <= 0.04f) msk |= 1u << j;     // f32(0.2**2) boundary, exact
                }
            }
            int myc = __popc(msk);
            int base = 0;
            if (myc) base = atomicAdd(cN, myc);          // one atomic per hitting thread
            unsigned mm = msk;
            while (mm) {
                int j = __builtin_ctz(mm); mm &= mm - 1;
                if (base < 1024) { cD[base] = d2a[j]; cI[base] = (unsigned short)(tid * 16 + j); }
                base++;
            }
            __syncthreads();   // B2
            int M = min(*cN, 1024);
            int n = min(M, K_);
            for (int i2 = tid; i2 < M; i2 += 256) {
                float di = cD[i2]; int ii = (int)cI[i2]; int r = 0;
                for (int j = 0; j < M; j++) {
                    float dj = cD[j];
                    r += (dj < di) || (dj == di && (int)cI[j] < ii);   // stable tie-break
                }
                if (r < K_) { nbrG[q * K_ + r] = (unsigned short)ii; sNbr[r] = (unsigned short)ii; }
            }
            if (tid == 0) { cnt[q] = n; atomicAdd(cntT, n); }
            __syncthreads();   // B3
            {   // gather x_j -> feat cols 0..63 (f16), zero rows >= n
                int row = tid >> 2, c4 = (tid & 3) * 16;
                half8 o0, o1;
                #pragma unroll
                for (int e = 0; e < 8; e++) { o0[e] = (_Float16)0.f; o1[e] = (_Float16)0.f; }
                if (row < n) {
                    const float4* xr = (const float4*)(x + ((size_t)b * N_ + sNbr[row]) * CIN + c4);
                    float4 v0 = xr[0], v1 = xr[1], v2 = xr[2], v3 = xr[3];
                    o0[0]=(_Float16)v0.x; o0[1]=(_Float16)v0.y; o0[2]=(_Float16)v0.z; o0[3]=(_Float16)v0.w;
                    o0[4]=(_Float16)v1.x; o0[5]=(_Float16)v1.y; o0[6]=(_Float16)v1.z; o0[7]=(_Float16)v1.w;
                    o1[0]=(_Float16)v2.x; o1[1]=(_Float16)v2.y; o1[2]=(_Float16)v2.z; o1[3]=(_Float16)v2.w;
                    o1[4]=(_Float16)v3.x; o1[5]=(_Float16)v3.y; o1[6]=(_Float16)v3.z; o1[7]=(_Float16)v3.w;
                }
                *(half8*)&sBuf[row * 104 + c4]     = o0;
                *(half8*)&sBuf[row * 104 + c4 + 8] = o1;
            }
            if (tid < 64) {   // cols 64..66 = pos_j - ctr, 67..95 = 0
                half8 z, o;
                #pragma unroll
                for (int e = 0; e < 8; e++) { z[e] = (_Float16)0.f; o[e] = (_Float16)0.f; }
                if (tid < n) {
                    int j = sNbr[tid];
                    const float* pj = pos + ((size_t)b * N_ + j) * 3;
                    o[0] = (_Float16)(pj[0] - cx); o[1] = (_Float16)(pj[1] - cy); o[2] = (_Float16)(pj[2] - cz);
                }
                *(half8*)&sBuf[tid * 104 + 64] = o;
                *(half8*)&sBuf[tid * 104 + 72] = z;
                *(half8*)&sBuf[tid * 104 + 80] = z;
                *(half8*)&sBuf[tid * 104 + 88] = z;
            }
            __syncthreads();   // B4
            floatx4 acc[4][2];
            #pragma unroll
            for (int rt = 0; rt < 4; rt++)
                #pragma unroll
                for (int nt = 0; nt < 2; nt++)
                    #pragma unroll
                    for (int r = 0; r < 4; r++) acc[rt][nt][r] = 0.f;
            #pragma unroll
            for (int ks = 0; ks < 3; ks++) {
                half8 av[4];
                #pragma unroll
                for (int rt = 0; rt < 4; rt++)
                    av[rt] = *(const half8*)&sBuf[(rt * 16 + lr) * 104 + ks * 32 + lq * 8];
                #pragma unroll
                for (int rt = 0; rt < 4; rt++)
                    #pragma unroll
                    for (int nt = 0; nt < 2; nt++)
                        acc[rt][nt] = __builtin_amdgcn_mfma_f32_16x16x32_f16(av[rt], w0f[ks][nt], acc[rt][nt], 0, 0, 0);
            }
            #pragma unroll
            for (int nt = 0; nt < 2; nt++) {
                int col = colbase + 16 * nt;
                float bias = sB0v[col];
                #pragma unroll
                for (int rt = 0; rt < 4; rt++) {
                    int r0 = rt * 16 + lq * 4;
                    #pragma unroll
                    for (int r = 0; r < 4; r++) {
                        float v = acc[rt][nt][r] + bias;
                        if (r0 + r < n) { runS1[nt] += v; runS2[nt] += v * v; }
                        if (doH0) sOut[(r0 + r) * 128 + col] = (_Float16)v;
                    }
                }
            }
            if (doH0) {   // dump h0 (free: HBM idle during k_front)
                __syncthreads();
                const float4* src = (const float4*)sOut;
                float4* dst = (float4*)(h0 + (size_t)q * 8192);
                for (int i2 = tid; i2 < 1024; i2 += 256) dst[i2] = src[i2];
            }
        }
        #pragma unroll
        for (int nt = 0; nt < 2; nt++) {
            float s1 = runS1[nt], s2 = runS2[nt];
            s1 += __shfl_xor(s1, 16); s1 += __shfl_xor(s1, 32);
            s2 += __shfl_xor(s2, 16); s2 += __shfl_xor(s2, 32);
            if (lq == 0) {   // fixed-point (2^20) i64 atomics: deterministic
                int col = colbase + 16 * nt;
                atomicAdd(&statsOut[col],       (unsigned long long)(long long)llrintf(s1 * 1048576.f));
                atomicAdd(&statsOut[128 + col], (unsigned long long)(long long)llrintf(s2 * 1048576.f));
            }
        }
    }
}

// ---------------------------------------------------------------- BN params
__global__ void k_bnparam(const unsigned long long* __restrict__ stats, const int* __restrict__ cntT,
        const float* __restrict__ g, const float* __restrict__ be,
        float* __restrict__ scale, float* __restrict__ shift) {
    int t = threadIdx.x;
    double c = (double)(*cntT);
    double mean = (double)(long long)stats[t] * (1.0 / 1048576.0) / c;
    double ex2  = (double)(long long)stats[128 + t] * (1.0 / 1048576.0) / c;
    double var = ex2 - mean * mean;
    if (var < 0.0) var = 0.0;
    double sc = (double)g[t] / sqrt(var + 1e-5);
    scale[t] = (float)sc;
    shift[t] = (float)((double)be[t] - mean * sc);
}

// ---------------------------------------------------------------- tail MLP (r8 col-sliced)
// BIG=1: load h0 (f16) instead of gather+GEMM0 recompute (saves ~40%/pass).
// BIG=0: r9 recompute fallback.
template<int STAGE, int BIG>
__global__ __launch_bounds__(256, 2) void k_mlp(const float* __restrict__ x,
        const float* __restrict__ pos, const float* __restrict__ ctr,
        const unsigned short* __restrict__ nbr, const int* __restrict__ cnt,
        const _Float16* __restrict__ w0t, const _Float16* __restrict__ w1t,
        const _Float16* __restrict__ w2t,
        const float* __restrict__ b0, const float* __restrict__ b1,
        const float* __restrict__ b2,
        const float* __restrict__ sc0, const float* __restrict__ sh0,
        const float* __restrict__ sc1, const float* __restrict__ sh1,
        unsigned long long* __restrict__ statsOut, const _Float16* __restrict__ h0,
        float* __restrict__ outF) {
    __shared__ __align__(16) _Float16 sBuf[64 * 136];   // feat(104) / h'(136)
    __shared__ unsigned short sNbr[64];
    __shared__ float sB0v[128];
    __shared__ float sB1v[128];
    __shared__ float sSc0[128];
    __shared__ float sSh0[128];
    __shared__ float sB2v[(STAGE >= 2) ? 128 : 4];
    __shared__ float sSc1[(STAGE >= 2) ? 128 : 4];
    __shared__ float sSh1[(STAGE >= 2) ? 128 : 4];

    int tid = threadIdx.x, wid = tid >> 6, lane = tid & 63;
    int lr = lane & 15, lq = lane >> 4;
    int colbase = 32 * wid + lr;

    half8 w0f[BIG ? 1 : 3][2];
    if constexpr (!BIG)
        #pragma unroll
        for (int ks = 0; ks < 3; ks++)
            #pragma unroll
            for (int nt = 0; nt < 2; nt++)
                w0f[ks][nt] = *(const half8*)(w0t + (colbase + 16*nt) * 96 + ks * 32 + lq * 8);
    half8 w1f[4][2];
    #pragma unroll
    for (int ks = 0; ks < 4; ks++)
        #pragma unroll
        for (int nt = 0; nt < 2; nt++)
            w1f[ks][nt] = *(const half8*)(w1t + (colbase + 16*nt) * 128 + ks * 32 + lq * 8);
    half8 w2f[(STAGE >= 2) ? 4 : 1][2];
    if constexpr (STAGE >= 2)
        #pragma unroll
        for (int ks = 0; ks < 4; ks++)
            #pragma unroll
            for (int nt = 0; nt < 2; nt++)
                w2f[ks][nt] = *(const half8*)(w2t + (colbase + 16*nt) * 128 + ks * 32 + lq * 8);

    if (tid < 128) {
        sB0v[tid] = b0[tid];
        sB1v[tid] = b1[tid]; sSc0[tid] = sc0[tid]; sSh0[tid] = sh0[tid];
        if constexpr (STAGE >= 2) { sB2v[tid] = b2[tid]; sSc1[tid] = sc1[tid]; sSh1[tid] = sh1[tid]; }
    }
    float runS1[2] = {0.f, 0.f}, runS2[2] = {0.f, 0.f};

    for (int qq = 0; qq < 8; qq++) {
        int q = blockIdx.x * 8 + qq;
        int b = q >> 11;
        __syncthreads();                    // prior-iter sBuf readers done
        int n = cnt[q];
        floatx4 acc[4][2];

        if constexpr (BIG) {
            // ---- load h0 (f16), BN0 + ReLU -> sBuf(136)
            int row = tid >> 2, c0 = (tid & 3) * 32;
            const _Float16* hp = h0 + (size_t)q * 8192 + row * 128 + c0;
            #pragma unroll
            for (int g2 = 0; g2 < 4; g2++) {
                half8 hv = *(const half8*)(hp + g2 * 8);
                half8 ov;
                #pragma unroll
                for (int e = 0; e < 8; e++) {
                    int c = c0 + g2 * 8 + e;
                    float v = (float)hv[e] * sSc0[c] + sSh0[c];
                    ov[e] = (_Float16)fmaxf(v, 0.f);
                }
                *(half8*)&sBuf[row * 136 + c0 + g2 * 8] = ov;
            }
            __syncthreads();
        } else {
            if (tid < 64) sNbr[tid] = nbr[q * K_ + tid];
            __syncthreads();
            {   // gather x_j -> feat cols 0..63 (f16), zero rows >= n
                int row = tid >> 2, c4 = (tid & 3) * 16;
                half8 o0, o1;
                #pragma unroll
                for (int e = 0; e < 8; e++) { o0[e] = (_Float16)0.f; o1[e] = (_Float16)0.f; }
                if (row < n) {
                    const float4* xr = (const float4*)(x + ((size_t)b * N_ + sNbr[row]) * CIN + c4);
                    float4 v0 = xr[0], v1 = xr[1], v2 = xr[2], v3 = xr[3];
                    o0[0]=(_Float16)v0.x; o0[1]=(_Float16)v0.y; o0[2]=(_Float16)v0.z; o0[3]=(_Float16)v0.w;
                    o0[4]=(_Float16)v1.x; o0[5]=(_Float16)v1.y; o0[6]=(_Float16)v1.z; o0[7]=(_Float16)v1.w;
                    o1[0]=(_Float16)v2.x; o1[1]=(_Float16)v2.y; o1[2]=(_Float16)v2.z; o1[3]=(_Float16)v2.w;
                    o1[4]=(_Float16)v3.x; o1[5]=(_Float16)v3.y; o1[6]=(_Float16)v3.z; o1[7]=(_Float16)v3.w;
                }
                *(half8*)&sBuf[row * 104 + c4]     = o0;
                *(half8*)&sBuf[row * 104 + c4 + 8] = o1;
            }
            if (tid < 64) {
                half8 z, o;
                #pragma unroll
                for (int e = 0; e < 8; e++) { z[e] = (_Float16)0.f; o[e] = (_Float16)0.f; }
                if (tid < n) {
                    int j = sNbr[tid];
                    float cx = ctr[q*3], cy = ctr[q*3+1], cz = ctr[q*3+2];
                    const float* pj = pos + ((size_t)b * N_ + j) * 3;
                    o[0] = (_Float16)(pj[0] - cx); o[1] = (_Float16)(pj[1] - cy); o[2] = (_Float16)(pj[2] - cz);
                }
                *(half8*)&sBuf[tid * 104 + 64] = o;
                *(half8*)&sBuf[tid * 104 + 72] = z;
                *(half8*)&sBuf[tid * 104 + 80] = z;
                *(half8*)&sBuf[tid * 104 + 88] = z;
            }
            __syncthreads();
            // ---- GEMM0: K=96
            #pragma unroll
            for (int rt = 0; rt < 4; rt++)
                #pragma unroll
                for (int nt = 0; nt < 2; nt++)
                    #pragma unroll
                    for (int r = 0; r < 4; r++) acc[rt][nt][r] = 0.f;
            #pragma unroll
            for (int ks = 0; ks < 3; ks++) {
                half8 av[4];
                #pragma unroll
                for (int rt = 0; rt < 4; rt++)
                    av[rt] = *(const half8*)&sBuf[(rt * 16 + lr) * 104 + ks * 32 + lq * 8];
                #pragma unroll
                for (int rt = 0; rt < 4; rt++)
                    #pragma unroll
                    for (int nt = 0; nt < 2; nt++)
                        acc[rt][nt] = __builtin_amdgcn_mfma_f32_16x16x32_f16(av[rt], w0f[ks][nt], acc[rt][nt], 0, 0, 0);
            }
            __syncthreads();
            // BN0 + ReLU -> f16 A-matrix for GEMM1
            #pragma unroll
            for (int nt = 0; nt < 2; nt++) {
                int col = colbase + 16 * nt;
                float bias = sB0v[col], s = sSc0[col], t2 = sSh0[col];
                #pragma unroll
                for (int rt = 0; rt < 4; rt++) {
                    int r0 = rt * 16 + lq * 4;
                    #pragma unroll
                    for (int r = 0; r < 4; r++) {
                        float v = (acc[rt][nt][r] + bias) * s + t2;
                        sBuf[(r0 + r) * 136 + col] = (_Float16)fmaxf(v, 0.f);
                    }
                }
            }
            __syncthreads();
        }

        // ---- GEMM1: K=128
        #pragma unroll
        for (int rt = 0; rt < 4; rt++)
            #pragma unroll
            for (int nt = 0; nt < 2; nt++)
                #pragma unroll
                for (int r = 0; r < 4; r++) acc[rt][nt][r] = 0.f;
        #pragma unroll
        for (int ks = 0; ks < 4; ks++) {
            half8 av[4];
            #pragma unroll
            for (int rt = 0; rt < 4; rt++)
                av[rt] = *(const half8*)&sBuf[(rt * 16 + lr) * 136 + ks * 32 + lq * 8];
            #pragma unroll
            for (int rt = 0; rt < 4; rt++)
                #pragma unroll
                for (int nt = 0; nt < 2; nt++)
                    acc[rt][nt] = __builtin_amdgcn_mfma_f32_16x16x32_f16(av[rt], w1f[ks][nt], acc[rt][nt], 0, 0, 0);
        }

        if constexpr (STAGE == 1) {
            #pragma unroll
            for (int nt = 0; nt < 2; nt++) {
                int col = colbase + 16 * nt;
                float bias = sB1v[col];
                #pragma unroll
                for (int rt = 0; rt < 4; rt++) {
                    int r0 = rt * 16 + lq * 4;
                    #pragma unroll
                    for (int r = 0; r < 4; r++) {
                        float v = acc[rt][nt][r] + bias;
                        if (r0 + r < n) { runS1[nt] += v; runS2[nt] += v * v; }
                    }
                }
            }
        } else {
            __syncthreads();            // GEMM1 A-reads done before overwrite
            // BN1 + ReLU -> f16 A-matrix for GEMM2
            #pragma unroll
            for (int nt = 0; nt < 2; nt++) {
                int col = colbase + 16 * nt;
                float bias = sB1v[col], s = sSc1[col], t2 = sSh1[col];
                #pragma unroll
                for (int rt = 0; rt < 4; rt++) {
                    int r0 = rt * 16 + lq * 4;
                    #pragma unroll
                    for (int r = 0; r < 4; r++) {
                        float v = (acc[rt][nt][r] + bias) * s + t2;
                        sBuf[(r0 + r) * 136 + col] = (_Float16)fmaxf(v, 0.f);
                    }
                }
            }
            __syncthreads();
            // ---- GEMM2: K=128
            #pragma unroll
            for (int rt = 0; rt < 4; rt++)
                #pragma unroll
                for (int nt = 0; nt < 2; nt++)
                    #pragma unroll
                    for (int r = 0; r < 4; r++) acc[rt][nt][r] = 0.f;
            #pragma unroll
            for (int ks = 0; ks < 4; ks++) {
                half8 av[4];
                #pragma unroll
                for (int rt = 0; rt < 4; rt++)
                    av[rt] = *(const half8*)&sBuf[(rt * 16 + lr) * 136 + ks * 32 + lq * 8];
                #pragma unroll
                for (int rt = 0; rt < 4; rt++)
                    #pragma unroll
                    for (int nt = 0; nt < 2; nt++)
                        acc[rt][nt] = __builtin_amdgcn_mfma_f32_16x16x32_f16(av[rt], w2f[ks][nt], acc[rt][nt], 0, 0, 0);
            }
            // masked max over all rows (wave owns its cols) -> direct store
            #pragma unroll
            for (int nt = 0; nt < 2; nt++) {
                int col = colbase + 16 * nt;
                float bias = sB2v[col];
                float m = -__builtin_inff();
                #pragma unroll
                for (int rt = 0; rt < 4; rt++) {
                    int r0 = rt * 16 + lq * 4;
                    #pragma unroll
                    for (int r = 0; r < 4; r++)
                        if (r0 + r < n) m = fmaxf(m, acc[rt][nt][r] + bias);
                }
                m = fmaxf(m, __shfl_xor(m, 16));
                m = fmaxf(m, __shfl_xor(m, 32));
                if (lq == 0) outF[(size_t)q * 128 + col] = m;
            }
        }
    }
    if constexpr (STAGE == 1) {
        #pragma unroll
        for (int nt = 0; nt < 2; nt++) {
            float s1 = runS1[nt], s2 = runS2[nt];
            s1 += __shfl_xor(s1, 16); s1 += __shfl_xor(s1, 32);
            s2 += __shfl_xor(s2, 16); s2 += __shfl_xor(s2, 32);
            if (lq == 0) {
                int col = colbase + 16 * nt;
                atomicAdd(&statsOut[col],       (unsigned long long)(long long)llrintf(s1 * 1048576.f));
                atomicAdd(&statsOut[128 + col], (unsigned long long)(long long)llrintf(s2 * 1048576.f));
            }
        }
    }
}

// ---------------------------------------------------------------- launch
extern "C" void kernel_launch(void* const* d_in, const int* in_sizes, int n_in,
                              void* d_out, int out_size, void* d_ws, size_t ws_size,
                              hipStream_t stream) {
    const float* x   = (const float*)d_in[0];
    const float* pos = (const float*)d_in[1];
    const float* W0  = (const float*)d_in[3];
    const float* b0  = (const float*)d_in[4];
    const float* g0  = (const float*)d_in[5];
    const float* be0 = (const float*)d_in[6];
    const float* W1  = (const float*)d_in[7];
    const float* b1  = (const float*)d_in[8];
    const float* g1  = (const float*)d_in[9];
    const float* be1 = (const float*)d_in[10];
    const float* W2  = (const float*)d_in[11];
    const float* b2  = (const float*)d_in[12];

    char* ws = (char*)d_ws;
    unsigned long long* stats = (unsigned long long*)(ws + WS_STATS);
    int* cntT = (int*)(ws + WS_CNTT);
    _Float16* w0t = (_Float16*)(ws + WS_W0T);
    _Float16* w1t = (_Float16*)(ws + WS_W1T);
    _Float16* w2t = (_Float16*)(ws + WS_W2T);
    float* sc0 = (float*)(ws + WS_SC0);
    float* sh0 = (float*)(ws + WS_SH0);
    float* sc1 = (float*)(ws + WS_SC1);
    float* sh1 = (float*)(ws + WS_SH1);
    int* cnt = (int*)(ws + WS_CNT);
    unsigned short* nbr = (unsigned short*)(ws + WS_NBR);
    int* prog = (int*)(ws + WS_PROG);
    _Float16* h0 = (_Float16*)(ws + WS_H0);
    int big = (ws_size >= (size_t)WS_H0 + H0_BYTES) ? 1 : 0;

    float* outF = (float*)d_out;                  // [16384,128]
    float* outCtr = (float*)d_out + 2097152;      // [16384,3]
    float* outBatch = (float*)d_out + 2146304;    // [16384]

    k_prep<<<176, 256, 0, stream>>>(W0, W1, W2, w0t, w1t, w2t, stats, cntT, prog);
    k_front<<<256, 256, 0, stream>>>(pos, x, w0t, b0, outCtr, outBatch, nbr, cnt, cntT,
            stats, prog, h0, big);
    k_bnparam<<<1, 128, 0, stream>>>(stats, cntT, g0, be0, sc0, sh0);
    if (big) {
        k_mlp<1,1><<<Q_/8, 256, 0, stream>>>(x, pos, outCtr, nbr, cnt, w0t, w1t, w2t,
                b0, b1, b2, sc0, sh0, sc1, sh1, stats + 256, h0, outF);
        k_bnparam<<<1, 128, 0, stream>>>(stats + 256, cntT, g1, be1, sc1, sh1);
        k_mlp<2,1><<<Q_/8, 256, 0, stream>>>(x, pos, outCtr, nbr, cnt, w0t, w1t, w2t,
                b0, b1, b2, sc0, sh0, sc1, sh1, stats, h0, outF);
    } else {
        k_mlp<1,0><<<Q_/8, 256, 0, stream>>>(x, pos, outCtr, nbr, cnt, w0t, w1t, w2t,
                b0, b1, b2, sc0, sh0, sc1, sh1, stats + 256, h0, outF);
        k_bnparam<<<1, 128, 0, stream>>>(stats + 256, cntT, g1, be1, sc1, sh1);
        k_mlp<2,0><<<Q_/8, 256, 0, stream>>>(x, pos, outCtr, nbr, cnt, w0t, w1t, w2t,
                b0, b1, b2, sc0, sh0, sc1, sh1, stats, h0, outF);
    }
}

// Round 11
// 1743.736 us; speedup vs baseline: 1.0033x; 1.0033x over previous
//
#include <hip/hip_runtime.h>

typedef _Float16 half8 __attribute__((ext_vector_type(8)));
typedef float floatx4 __attribute__((ext_vector_type(4)));

#define B_   8
#define N_   4096
#define S_   2048
#define K_   64
#define CIN  64
#define HID_ 128
#define Q_   (B_*S_)
#define NCONS 248            // consumer blocks in k_front (blocks 8..255)

// ---------------- ws layout (bytes), ~2.33 MB ----------------
#define WS_STATS 0u          // 512 u64 (sum0,sq0,sum1,sq1) = 4096
#define WS_CNTT  4096u       // int, padded
#define WS_W0T   4224u       // 128*96 f16 = 24576
#define WS_W1T   28800u      // 128*128 f16 = 32768
#define WS_W2T   61568u      // 32768
#define WS_CNT   96384u      // 16384 int = 65536
#define WS_NBR   161920u     // 16384*64 u16 = 2097152
#define WS_PROG  2259072u    // 8 int flags (+pad)
#define WS_IDX   2259200u    // 16384 int = 65536 (fps order indices)

// ---------------------------------------------------------------- prep
__global__ __launch_bounds__(256) void k_prep(const float* __restrict__ W0,
        const float* __restrict__ W1, const float* __restrict__ W2,
        _Float16* __restrict__ w0t, _Float16* __restrict__ w1t, _Float16* __restrict__ w2t,
        unsigned long long* __restrict__ stats, int* __restrict__ cntT, int* __restrict__ prog) {
    int t = blockIdx.x * 256 + threadIdx.x;
    if (t < 128 * 96) {                       // W0T[c][k], k padded 67->96 with 0
        int c = t / 96, k = t - c * 96;
        w0t[t] = (k < 67) ? (_Float16)W0[k * 128 + c] : (_Float16)0.f;
    } else if (t < 128 * 96 + 16384) {        // W1T[c][k]
        int u = t - 128 * 96; int c = u >> 7, k = u & 127;
        w1t[u] = (_Float16)W1[k * 128 + c];
    } else if (t < 128 * 96 + 32768) {        // W2T[c][k]
        int u = t - 128 * 96 - 16384; int c = u >> 7, k = u & 127;
        w2t[u] = (_Float16)W2[k * 128 + c];
    }
    if (t < 512) stats[t] = 0ULL;
    if (t < 8) prog[t] = 0;
    if (t == 0) *cntT = 0;
}

// ---------------------------------------------------------------- front
// Blocks 0..7: r3-exact FPS loop (measured floor; r4/r5/r7 variants all
// regressed) + INDEX-ONLY flush every 64 iters: 64 packed int stores (one
// ~256B burst) -> barrier drain (cheap now) -> release prog[b]. Centroid
// f32 coords are reconstructed by consumers from pos[b,idx] — an immutable
// input, so values are bit-identical and need no coherence. outCtr/outBatch
// are bulk-written in the producer epilogue (r3 pattern).
// Blocks 8..255: per-query consumers — spin (s_sleep) on prog[b], read idx,
// nbr exact-rank-select + gather + GEMM0 + stats0 (r8 col-sliced, weights
// in registers; stats via order-independent fixed-point i64 atomics).
template<int CTRL>
__device__ inline unsigned long long dpp64(unsigned long long v) {
    int lo = (int)(unsigned)v, hi = (int)(unsigned)(v >> 32);
    int nlo = __builtin_amdgcn_update_dpp(lo, lo, CTRL, 0xF, 0xF, false);
    int nhi = __builtin_amdgcn_update_dpp(hi, hi, CTRL, 0xF, 0xF, false);
    return ((unsigned long long)(unsigned)nhi << 32) | (unsigned long long)(unsigned)nlo;
}
__device__ inline unsigned long long u64max(unsigned long long a, unsigned long long b) {
    return (b > a) ? b : a;
}

__global__ __launch_bounds__(256) void k_front(const float* __restrict__ pos,
        const float* __restrict__ x, const _Float16* __restrict__ w0t,
        const float* __restrict__ b0, float* __restrict__ outCtr, float* __restrict__ outBatch,
        unsigned short* __restrict__ nbrG, int* __restrict__ cnt, int* __restrict__ cntT,
        unsigned long long* __restrict__ statsOut, int* prog, int* idxG) {
    __shared__ __align__(16) char uLDS[84480];   // >81920 -> 1 block/CU
    int tid = threadIdx.x;

    if (blockIdx.x < 8) {
        // ================= PRODUCER =================
        float4* sP4 = (float4*)uLDS;                               // 64 KB
        unsigned long long* red = (unsigned long long*)(uLDS + 65536);
        unsigned short* sSeq = (unsigned short*)(uLDS + 65600);    // 4 KB
        int b = blockIdx.x;
        const float* P = pos + (size_t)b * N_ * 3;

        float px[16], py[16], pz[16], md[16];
        {
            const float4* vp = (const float4*)(P + tid * 48);
            float a[48];
            #pragma unroll
            for (int v = 0; v < 12; v++) {
                float4 t4 = vp[v];
                a[v*4] = t4.x; a[v*4+1] = t4.y; a[v*4+2] = t4.z; a[v*4+3] = t4.w;
            }
            #pragma unroll
            for (int j = 0; j < 16; j++) {
                px[j] = a[3*j]; py[j] = a[3*j+1]; pz[j] = a[3*j+2];
                md[j] = __builtin_inff();
                sP4[tid * 16 + j] = make_float4(px[j], py[j], pz[j], 0.f);
            }
        }
        __syncthreads();

        int last = 0;
        for (int i = 0; i < S_; i++) {
            float4 cc = sP4[last];                       // broadcast ds_read_b128
            if (tid == (i & 255)) sSeq[i] = (unsigned short)last;
            unsigned long long best;
            {
                #pragma clang fp contract(off)
                float bv = -1.f; unsigned bi = 0;
                #pragma unroll
                for (int j = 0; j < 16; j++) {
                    float dx = px[j] - cc.x, dy = py[j] - cc.y, dz = pz[j] - cc.z;
                    float d = (dx * dx + dy * dy) + dz * dz;   // numpy order, no fma
                    float m = fminf(md[j], d); md[j] = m;
                    if (m > bv) { bv = m; bi = (unsigned)j; } // strict > => first index
                }
                best = ((unsigned long long)__float_as_uint(bv) << 32)
                     | (unsigned long long)(0xFFFFu - (unsigned)(tid * 16) - bi);
            }
            best = u64max(best, dpp64<0x111>(best));   // row_shr:1
            best = u64max(best, dpp64<0x112>(best));   // row_shr:2
            best = u64max(best, dpp64<0x114>(best));   // row_shr:4
            best = u64max(best, dpp64<0x118>(best));   // row_shr:8
            best = u64max(best, dpp64<0x142>(best));   // row_bcast:15
            best = u64max(best, dpp64<0x143>(best));   // row_bcast:31 -> lane63 = wave max
            if ((tid & 63) == 63) red[(i & 1) * 4 + (tid >> 6)] = best;
            __syncthreads();   // double-buffered red: one barrier/iter race-free
            ulonglong2 ra = *(const ulonglong2*)&red[(i & 1) * 4];
            ulonglong2 rb = *(const ulonglong2*)&red[(i & 1) * 4 + 2];
            unsigned long long g = u64max(u64max(ra.x, ra.y), u64max(rb.x, rb.y));
            last = (int)(0xFFFFu - (unsigned)(g & 0xFFFFu));
            if ((i & 63) == 63) {   // index-only flush: one ~256B burst + cheap drain
                if (tid < 64) {
                    int ii = i - 63 + tid;
                    __hip_atomic_store(&idxG[b * S_ + ii], (int)sSeq[ii],
                                       __ATOMIC_RELAXED, __HIP_MEMORY_SCOPE_AGENT);
                }
                __syncthreads();   // drains vmcnt: stores at coherence point
                if (tid == 0)
                    __hip_atomic_store(&prog[b], i + 1, __ATOMIC_RELEASE, __HIP_MEMORY_SCOPE_AGENT);
            }
        }
        __syncthreads();
        for (int i = tid; i < S_; i += 256) {    // bulk epilogue write (once)
            int o = b * S_ + i;
            float4 c = sP4[sSeq[i]];
            outCtr[o*3] = c.x; outCtr[o*3+1] = c.y; outCtr[o*3+2] = c.z;
            outBatch[o] = (float)b;
        }
    } else {
        // ================= CONSUMER =================
        float* cD = (float*)uLDS;                          // 4 KB
        unsigned short* cI = (unsigned short*)(uLDS + 4096);
        unsigned short* sNbr = (unsigned short*)(uLDS + 6144);
        float* sB0v = (float*)(uLDS + 6272);
        float* sCtr = (float*)(uLDS + 6784);
        int* cN = (int*)(uLDS + 6800);
        _Float16* sBuf = (_Float16*)(uLDS + 6912);         // 64*104 f16

        int wid = tid >> 6, lane = tid & 63;
        int lr = lane & 15, lq = lane >> 4;
        int colbase = 32 * wid + lr;
        half8 w0f[3][2];
        #pragma unroll
        for (int ks = 0; ks < 3; ks++)
            #pragma unroll
            for (int nt = 0; nt < 2; nt++)
                w0f[ks][nt] = *(const half8*)(w0t + (colbase + 16*nt) * 96 + ks * 32 + lq * 8);
        if (tid < 128) sB0v[tid] = b0[tid];
        float runS1[2] = {0.f, 0.f}, runS2[2] = {0.f, 0.f};

        for (int k = (int)blockIdx.x - 8; k < Q_; k += NCONS) {
            int i = k >> 3, b = k & 7;
            int q = (b << 11) + i;
            if (tid == 0) {
                while (__hip_atomic_load(&prog[b], __ATOMIC_ACQUIRE, __HIP_MEMORY_SCOPE_AGENT) <= i)
                    __builtin_amdgcn_s_sleep(32);
                int idx = __hip_atomic_load(&idxG[b * S_ + i], __ATOMIC_RELAXED, __HIP_MEMORY_SCOPE_AGENT);
                const float* pc = pos + ((size_t)b * N_ + idx) * 3;   // immutable input:
                sCtr[0] = pc[0]; sCtr[1] = pc[1]; sCtr[2] = pc[2];    // bit-identical coords
                *cN = 0;
            }
            __syncthreads();   // B1
            float cx = sCtr[0], cy = sCtr[1], cz = sCtr[2];
            const float* P = pos + (size_t)b * N_ * 3;
            float a[48];
            {
                const float4* vp = (const float4*)(P + (size_t)tid * 48);
                #pragma unroll
                for (int v = 0; v < 12; v++) {
                    float4 t4 = vp[v];
                    a[v*4] = t4.x; a[v*4+1] = t4.y; a[v*4+2] = t4.z; a[v*4+3] = t4.w;
                }
            }
            unsigned msk = 0;
            float d2a[16];
            {
                #pragma clang fp contract(off)
                #pragma unroll
                for (int j = 0; j < 16; j++) {
                    float dx = cx - a[3*j], dy = cy - a[3*j+1], dz = cz - a[3*j+2];
                    float d2 = (dx * dx + dy * dy) + dz * dz;
                    d2a[j] = d2;
                    if (d2 <= 0.04f) msk |= 1u << j;     // f32(0.2**2) boundary, exact
                }
            }
            int myc = __popc(msk);
            int base = 0;
            if (myc) base = atomicAdd(cN, myc);          // one atomic per hitting thread
            unsigned mm = msk;
            while (mm) {
                int j = __builtin_ctz(mm); mm &= mm - 1;
                if (base < 1024) { cD[base] = d2a[j]; cI[base] = (unsigned short)(tid * 16 + j); }
                base++;
            }
            __syncthreads();   // B2
            int M = min(*cN, 1024);
            int n = min(M, K_);
            for (int i2 = tid; i2 < M; i2 += 256) {
                float di = cD[i2]; int ii = (int)cI[i2]; int r = 0;
                for (int j = 0; j < M; j++) {
                    float dj = cD[j];
                    r += (dj < di) || (dj == di && (int)cI[j] < ii);   // stable tie-break
                }
                if (r < K_) { nbrG[q * K_ + r] = (unsigned short)ii; sNbr[r] = (unsigned short)ii; }
            }
            if (tid == 0) { cnt[q] = n; atomicAdd(cntT, n); }
            __syncthreads();   // B3
            {   // gather x_j -> feat cols 0..63 (f16), zero rows >= n
                int row = tid >> 2, c4 = (tid & 3) * 16;
                half8 o0, o1;
                #pragma unroll
                for (int e = 0; e < 8; e++) { o0[e] = (_Float16)0.f; o1[e] = (_Float16)0.f; }
                if (row < n) {
                    const float4* xr = (const float4*)(x + ((size_t)b * N_ + sNbr[row]) * CIN + c4);
                    float4 v0 = xr[0], v1 = xr[1], v2 = xr[2], v3 = xr[3];
                    o0[0]=(_Float16)v0.x; o0[1]=(_Float16)v0.y; o0[2]=(_Float16)v0.z; o0[3]=(_Float16)v0.w;
                    o0[4]=(_Float16)v1.x; o0[5]=(_Float16)v1.y; o0[6]=(_Float16)v1.z; o0[7]=(_Float16)v1.w;
                    o1[0]=(_Float16)v2.x; o1[1]=(_Float16)v2.y; o1[2]=(_Float16)v2.z; o1[3]=(_Float16)v2.w;
                    o1[4]=(_Float16)v3.x; o1[5]=(_Float16)v3.y; o1[6]=(_Float16)v3.z; o1[7]=(_Float16)v3.w;
                }
                *(half8*)&sBuf[row * 104 + c4]     = o0;
                *(half8*)&sBuf[row * 104 + c4 + 8] = o1;
            }
            if (tid < 64) {   // cols 64..66 = pos_j - ctr, 67..95 = 0
                half8 z, o;
                #pragma unroll
                for (int e = 0; e < 8; e++) { z[e] = (_Float16)0.f; o[e] = (_Float16)0.f; }
                if (tid < n) {
                    int j = sNbr[tid];
                    const float* pj = pos + ((size_t)b * N_ + j) * 3;
                    o[0] = (_Float16)(pj[0] - cx); o[1] = (_Float16)(pj[1] - cy); o[2] = (_Float16)(pj[2] - cz);
                }
                *(half8*)&sBuf[tid * 104 + 64] = o;
                *(half8*)&sBuf[tid * 104 + 72] = z;
                *(half8*)&sBuf[tid * 104 + 80] = z;
                *(half8*)&sBuf[tid * 104 + 88] = z;
            }
            __syncthreads();   // B4
            floatx4 acc[4][2];
            #pragma unroll
            for (int rt = 0; rt < 4; rt++)
                #pragma unroll
                for (int nt = 0; nt < 2; nt++)
                    #pragma unroll
                    for (int r = 0; r < 4; r++) acc[rt][nt][r] = 0.f;
            #pragma unroll
            for (int ks = 0; ks < 3; ks++) {
                half8 av[4];
                #pragma unroll
                for (int rt = 0; rt < 4; rt++)
                    av[rt] = *(const half8*)&sBuf[(rt * 16 + lr) * 104 + ks * 32 + lq * 8];
                #pragma unroll
                for (int rt = 0; rt < 4; rt++)
                    #pragma unroll
                    for (int nt = 0; nt < 2; nt++)
                        acc[rt][nt] = __builtin_amdgcn_mfma_f32_16x16x32_f16(av[rt], w0f[ks][nt], acc[rt][nt], 0, 0, 0);
            }
            #pragma unroll
            for (int nt = 0; nt < 2; nt++) {
                int col = colbase + 16 * nt;
                float bias = sB0v[col];
                #pragma unroll
                for (int rt = 0; rt < 4; rt++) {
                    int r0 = rt * 16 + lq * 4;
                    #pragma unroll
                    for (int r = 0; r < 4; r++) {
                        float v = acc[rt][nt][r] + bias;
                        if (r0 + r < n) { runS1[nt] += v; runS2[nt] += v * v; }
                    }
                }
            }
        }
        #pragma unroll
        for (int nt = 0; nt < 2; nt++) {
            float s1 = runS1[nt], s2 = runS2[nt];
            s1 += __shfl_xor(s1, 16); s1 += __shfl_xor(s1, 32);
            s2 += __shfl_xor(s2, 16); s2 += __shfl_xor(s2, 32);
            if (lq == 0) {   // fixed-point (2^20) i64 atomics: deterministic
                int col = colbase + 16 * nt;
                atomicAdd(&statsOut[col],       (unsigned long long)(long long)llrintf(s1 * 1048576.f));
                atomicAdd(&statsOut[128 + col], (unsigned long long)(long long)llrintf(s2 * 1048576.f));
            }
        }
    }
}

// ---------------------------------------------------------------- tail MLP (r8 col-sliced, recompute)
// BN params computed INLINE per block from the deterministic fixed-point
// stats (identical doubles in every block) — kills the k_bnparam launches.
// __launch_bounds__(256,3): 3 blocks/CU for gather-latency hiding.
template<int STAGE>
__global__ __launch_bounds__(256, 3) void k_mlp(const float* __restrict__ x,
        const float* __restrict__ pos, const float* __restrict__ ctr,
        const unsigned short* __restrict__ nbr, const int* __restrict__ cnt,
        const _Float16* __restrict__ w0t, const _Float16* __restrict__ w1t,
        const _Float16* __restrict__ w2t,
        const float* __restrict__ b0, const float* __restrict__ b1,
        const float* __restrict__ b2,
        const float* __restrict__ g0, const float* __restrict__ be0,
        const float* __restrict__ g1, const float* __restrict__ be1,
        const int* __restrict__ cntT,
        const unsigned long long* __restrict__ stats0,
        const unsigned long long* __restrict__ stats1,
        unsigned long long* __restrict__ statsOut, float* __restrict__ outF) {
    __shared__ __align__(16) _Float16 sBuf[64 * 136];   // feat(104) / h'(136)
    __shared__ unsigned short sNbr[64];
    __shared__ float sB0v[128];
    __shared__ float sB1v[128];
    __shared__ float sSc0[128];
    __shared__ float sSh0[128];
    __shared__ float sB2v[(STAGE >= 2) ? 128 : 4];
    __shared__ float sSc1[(STAGE >= 2) ? 128 : 4];
    __shared__ float sSh1[(STAGE >= 2) ? 128 : 4];

    int tid = threadIdx.x, wid = tid >> 6, lane = tid & 63;
    int lr = lane & 15, lq = lane >> 4;
    int colbase = 32 * wid + lr;

    if (tid < 128) {   // inline BN params (deterministic across blocks)
        double c = (double)(*cntT);
        double mean = (double)(long long)stats0[tid] * (1.0 / 1048576.0) / c;
        double ex2  = (double)(long long)stats0[128 + tid] * (1.0 / 1048576.0) / c;
        double var = ex2 - mean * mean;
        if (var < 0.0) var = 0.0;
        double sc = (double)g0[tid] / sqrt(var + 1e-5);
        sSc0[tid] = (float)sc;
        sSh0[tid] = (float)((double)be0[tid] - mean * sc);
        sB0v[tid] = b0[tid];
        sB1v[tid] = b1[tid];
        if constexpr (STAGE >= 2) {
            double mean1 = (double)(long long)stats1[tid] * (1.0 / 1048576.0) / c;
            double ex21  = (double)(long long)stats1[128 + tid] * (1.0 / 1048576.0) / c;
            double var1 = ex21 - mean1 * mean1;
            if (var1 < 0.0) var1 = 0.0;
            double sc1 = (double)g1[tid] / sqrt(var1 + 1e-5);
            sSc1[tid] = (float)sc1;
            sSh1[tid] = (float)((double)be1[tid] - mean1 * sc1);
            sB2v[tid] = b2[tid];
        }
    }

    half8 w0f[3][2];
    #pragma unroll
    for (int ks = 0; ks < 3; ks++)
        #pragma unroll
        for (int nt = 0; nt < 2; nt++)
            w0f[ks][nt] = *(const half8*)(w0t + (colbase + 16*nt) * 96 + ks * 32 + lq * 8);
    half8 w1f[4][2];
    #pragma unroll
    for (int ks = 0; ks < 4; ks++)
        #pragma unroll
        for (int nt = 0; nt < 2; nt++)
            w1f[ks][nt] = *(const half8*)(w1t + (colbase + 16*nt) * 128 + ks * 32 + lq * 8);
    half8 w2f[(STAGE >= 2) ? 4 : 1][2];
    if constexpr (STAGE >= 2)
        #pragma unroll
        for (int ks = 0; ks < 4; ks++)
            #pragma unroll
            for (int nt = 0; nt < 2; nt++)
                w2f[ks][nt] = *(const half8*)(w2t + (colbase + 16*nt) * 128 + ks * 32 + lq * 8);

    float runS1[2] = {0.f, 0.f}, runS2[2] = {0.f, 0.f};

    for (int qq = 0; qq < 8; qq++) {
        int q = blockIdx.x * 8 + qq;
        int b = q >> 11;
        __syncthreads();                    // prior-iter readers done; BN params visible
        int n = cnt[q];
        if (tid < 64) sNbr[tid] = nbr[q * K_ + tid];
        __syncthreads();
        {   // gather x_j -> feat cols 0..63 (f16), zero rows >= n
            int row = tid >> 2, c4 = (tid & 3) * 16;
            half8 o0, o1;
            #pragma unroll
            for (int e = 0; e < 8; e++) { o0[e] = (_Float16)0.f; o1[e] = (_Float16)0.f; }
            if (row < n) {
                const float4* xr = (const float4*)(x + ((size_t)b * N_ + sNbr[row]) * CIN + c4);
                float4 v0 = xr[0], v1 = xr[1], v2 = xr[2], v3 = xr[3];
                o0[0]=(_Float16)v0.x; o0[1]=(_Float16)v0.y; o0[2]=(_Float16)v0.z; o0[3]=(_Float16)v0.w;
                o0[4]=(_Float16)v1.x; o0[5]=(_Float16)v1.y; o0[6]=(_Float16)v1.z; o0[7]=(_Float16)v1.w;
                o1[0]=(_Float16)v2.x; o1[1]=(_Float16)v2.y; o1[2]=(_Float16)v2.z; o1[3]=(_Float16)v2.w;
                o1[4]=(_Float16)v3.x; o1[5]=(_Float16)v3.y; o1[6]=(_Float16)v3.z; o1[7]=(_Float16)v3.w;
            }
            *(half8*)&sBuf[row * 104 + c4]     = o0;
            *(half8*)&sBuf[row * 104 + c4 + 8] = o1;
        }
        if (tid < 64) {
            half8 z, o;
            #pragma unroll
            for (int e = 0; e < 8; e++) { z[e] = (_Float16)0.f; o[e] = (_Float16)0.f; }
            if (tid < n) {
                int j = sNbr[tid];
                float cx = ctr[q*3], cy = ctr[q*3+1], cz = ctr[q*3+2];
                const float* pj = pos + ((size_t)b * N_ + j) * 3;
                o[0] = (_Float16)(pj[0] - cx); o[1] = (_Float16)(pj[1] - cy); o[2] = (_Float16)(pj[2] - cz);
            }
            *(half8*)&sBuf[tid * 104 + 64] = o;
            *(half8*)&sBuf[tid * 104 + 72] = z;
            *(half8*)&sBuf[tid * 104 + 80] = z;
            *(half8*)&sBuf[tid * 104 + 88] = z;
        }
        __syncthreads();

        // ---- GEMM0: K=96
        floatx4 acc[4][2];
        #pragma unroll
        for (int rt = 0; rt < 4; rt++)
            #pragma unroll
            for (int nt = 0; nt < 2; nt++)
                #pragma unroll
                for (int r = 0; r < 4; r++) acc[rt][nt][r] = 0.f;
        #pragma unroll
        for (int ks = 0; ks < 3; ks++) {
            half8 av[4];
            #pragma unroll
            for (int rt = 0; rt < 4; rt++)
                av[rt] = *(const half8*)&sBuf[(rt * 16 + lr) * 104 + ks * 32 + lq * 8];
            #pragma unroll
            for (int rt = 0; rt < 4; rt++)
                #pragma unroll
                for (int nt = 0; nt < 2; nt++)
                    acc[rt][nt] = __builtin_amdgcn_mfma_f32_16x16x32_f16(av[rt], w0f[ks][nt], acc[rt][nt], 0, 0, 0);
        }
        __syncthreads();
        // BN0 + ReLU -> f16 A-matrix for GEMM1
        #pragma unroll
        for (int nt = 0; nt < 2; nt++) {
            int col = colbase + 16 * nt;
            float bias = sB0v[col], s = sSc0[col], t2 = sSh0[col];
            #pragma unroll
            for (int rt = 0; rt < 4; rt++) {
                int r0 = rt * 16 + lq * 4;
                #pragma unroll
                for (int r = 0; r < 4; r++) {
                    float v = (acc[rt][nt][r] + bias) * s + t2;
                    sBuf[(r0 + r) * 136 + col] = (_Float16)fmaxf(v, 0.f);
                }
            }
        }
        __syncthreads();
        // ---- GEMM1: K=128
        #pragma unroll
        for (int rt = 0; rt < 4; rt++)
            #pragma unroll
            for (int nt = 0; nt < 2; nt++)
                #pragma unroll
                for (int r = 0; r < 4; r++) acc[rt][nt][r] = 0.f;
        #pragma unroll
        for (int ks = 0; ks < 4; ks++) {
            half8 av[4];
            #pragma unroll
            for (int rt = 0; rt < 4; rt++)
                av[rt] = *(const half8*)&sBuf[(rt * 16 + lr) * 136 + ks * 32 + lq * 8];
            #pragma unroll
            for (int rt = 0; rt < 4; rt++)
                #pragma unroll
                for (int nt = 0; nt < 2; nt++)
                    acc[rt][nt] = __builtin_amdgcn_mfma_f32_16x16x32_f16(av[rt], w1f[ks][nt], acc[rt][nt], 0, 0, 0);
        }

        if constexpr (STAGE == 1) {
            #pragma unroll
            for (int nt = 0; nt < 2; nt++) {
                int col = colbase + 16 * nt;
                float bias = sB1v[col];
                #pragma unroll
                for (int rt = 0; rt < 4; rt++) {
                    int r0 = rt * 16 + lq * 4;
                    #pragma unroll
                    for (int r = 0; r < 4; r++) {
                        float v = acc[rt][nt][r] + bias;
                        if (r0 + r < n) { runS1[nt] += v; runS2[nt] += v * v; }
                    }
                }
            }
        } else {
            __syncthreads();            // GEMM1 A-reads done before overwrite
            // BN1 + ReLU -> f16 A-matrix for GEMM2
            #pragma unroll
            for (int nt = 0; nt < 2; nt++) {
                int col = colbase + 16 * nt;
                float bias = sB1v[col], s = sSc1[col], t2 = sSh1[col];
                #pragma unroll
                for (int rt = 0; rt < 4; rt++) {
                    int r0 = rt * 16 + lq * 4;
                    #pragma unroll
                    for (int r = 0; r < 4; r++) {
                        float v = (acc[rt][nt][r] + bias) * s + t2;
                        sBuf[(r0 + r) * 136 + col] = (_Float16)fmaxf(v, 0.f);
                    }
                }
            }
            __syncthreads();
            // ---- GEMM2: K=128
            #pragma unroll
            for (int rt = 0; rt < 4; rt++)
                #pragma unroll
                for (int nt = 0; nt < 2; nt++)
                    #pragma unroll
                    for (int r = 0; r < 4; r++) acc[rt][nt][r] = 0.f;
            #pragma unroll
            for (int ks = 0; ks < 4; ks++) {
                half8 av[4];
                #pragma unroll
                for (int rt = 0; rt < 4; rt++)
                    av[rt] = *(const half8*)&sBuf[(rt * 16 + lr) * 136 + ks * 32 + lq * 8];
                #pragma unroll
                for (int rt = 0; rt < 4; rt++)
                    #pragma unroll
                    for (int nt = 0; nt < 2; nt++)
                        acc[rt][nt] = __builtin_amdgcn_mfma_f32_16x16x32_f16(av[rt], w2f[ks][nt], acc[rt][nt], 0, 0, 0);
            }
            // masked max over all rows (wave owns its cols) -> direct store
            #pragma unroll
            for (int nt = 0; nt < 2; nt++) {
                int col = colbase + 16 * nt;
                float bias = sB2v[col];
                float m = -__builtin_inff();
                #pragma unroll
                for (int rt = 0; rt < 4; rt++) {
                    int r0 = rt * 16 + lq * 4;
                    #pragma unroll
                    for (int r = 0; r < 4; r++)
                        if (r0 + r < n) m = fmaxf(m, acc[rt][nt][r] + bias);
                }
                m = fmaxf(m, __shfl_xor(m, 16));
                m = fmaxf(m, __shfl_xor(m, 32));
                if (lq == 0) outF[(size_t)q * 128 + col] = m;
            }
        }
    }
    if constexpr (STAGE == 1) {
        #pragma unroll
        for (int nt = 0; nt < 2; nt++) {
            float s1 = runS1[nt], s2 = runS2[nt];
            s1 += __shfl_xor(s1, 16); s1 += __shfl_xor(s1, 32);
            s2 += __shfl_xor(s2, 16); s2 += __shfl_xor(s2, 32);
            if (lq == 0) {
                int col = colbase + 16 * nt;
                atomicAdd(&statsOut[col],       (unsigned long long)(long long)llrintf(s1 * 1048576.f));
                atomicAdd(&statsOut[128 + col], (unsigned long long)(long long)llrintf(s2 * 1048576.f));
            }
        }
    }
}

// ---------------------------------------------------------------- launch
extern "C" void kernel_launch(void* const* d_in, const int* in_sizes, int n_in,
                              void* d_out, int out_size, void* d_ws, size_t ws_size,
                              hipStream_t stream) {
    const float* x   = (const float*)d_in[0];
    const float* pos = (const float*)d_in[1];
    const float* W0  = (const float*)d_in[3];
    const float* b0  = (const float*)d_in[4];
    const float* g0  = (const float*)d_in[5];
    const float* be0 = (const float*)d_in[6];
    const float* W1  = (const float*)d_in[7];
    const float* b1  = (const float*)d_in[8];
    const float* g1  = (const float*)d_in[9];
    const float* be1 = (const float*)d_in[10];
    const float* W2  = (const float*)d_in[11];
    const float* b2  = (const float*)d_in[12];

    char* ws = (char*)d_ws;
    unsigned long long* stats = (unsigned long long*)(ws + WS_STATS);
    int* cntT = (int*)(ws + WS_CNTT);
    _Float16* w0t = (_Float16*)(ws + WS_W0T);
    _Float16* w1t = (_Float16*)(ws + WS_W1T);
    _Float16* w2t = (_Float16*)(ws + WS_W2T);
    int* cnt = (int*)(ws + WS_CNT);
    unsigned short* nbr = (unsigned short*)(ws + WS_NBR);
    int* prog = (int*)(ws + WS_PROG);
    int* idxG = (int*)(ws + WS_IDX);

    float* outF = (float*)d_out;                  // [16384,128]
    float* outCtr = (float*)d_out + 2097152;      // [16384,3]
    float* outBatch = (float*)d_out + 2146304;    // [16384]

    k_prep<<<176, 256, 0, stream>>>(W0, W1, W2, w0t, w1t, w2t, stats, cntT, prog);
    k_front<<<256, 256, 0, stream>>>(pos, x, w0t, b0, outCtr, outBatch, nbr, cnt, cntT,
            stats, prog, idxG);
    k_mlp<1><<<Q_/8, 256, 0, stream>>>(x, pos, outCtr, nbr, cnt, w0t, w1t, w2t,
            b0, b1, b2, g0, be0, g1, be1, cntT, stats, stats + 256, stats + 256, outF);
    k_mlp<2><<<Q_/8, 256, 0, stream>>>(x, pos, outCtr, nbr, cnt, w0t, w1t, w2t,
            b0, b1, b2, g0, be0, g1, be1, cntT, stats, stats + 256, stats, outF);
}

// Round 12
// 1713.285 us; speedup vs baseline: 1.0211x; 1.0178x over previous
//
#include <hip/hip_runtime.h>

typedef _Float16 half8 __attribute__((ext_vector_type(8)));
typedef float floatx4 __attribute__((ext_vector_type(4)));

#define B_   8
#define N_   4096
#define S_   2048
#define K_   64
#define CIN  64
#define HID_ 128
#define Q_   (B_*S_)
#define NCONS 248            // consumer blocks in k_front (blocks 8..255)
#define FLUSH 128            // producer flush period (iters)

// ---------------- ws layout (bytes), ~2.33 MB ----------------
#define WS_STATS 0u          // 512 u64 (sum0,sq0,sum1,sq1) = 4096
#define WS_CNTT  4096u       // int, padded
#define WS_W0T   4224u       // 128*96 f16 = 24576
#define WS_W1T   28800u      // 128*128 f16 = 32768
#define WS_W2T   61568u      // 32768
#define WS_CNT   96384u      // 16384 int = 65536
#define WS_NBR   161920u     // 16384*64 u16 = 2097152
#define WS_PROG  2259072u    // 8 flags, padded 256B apart = 2048
#define WS_IDX   2261120u    // 16384 int = 65536 (fps order indices)

// ---------------------------------------------------------------- prep
__global__ __launch_bounds__(256) void k_prep(const float* __restrict__ W0,
        const float* __restrict__ W1, const float* __restrict__ W2,
        _Float16* __restrict__ w0t, _Float16* __restrict__ w1t, _Float16* __restrict__ w2t,
        unsigned long long* __restrict__ stats, int* __restrict__ cntT, int* __restrict__ prog) {
    int t = blockIdx.x * 256 + threadIdx.x;
    if (t < 128 * 96) {                       // W0T[c][k], k padded 67->96 with 0
        int c = t / 96, k = t - c * 96;
        w0t[t] = (k < 67) ? (_Float16)W0[k * 128 + c] : (_Float16)0.f;
    } else if (t < 128 * 96 + 16384) {        // W1T[c][k]
        int u = t - 128 * 96; int c = u >> 7, k = u & 127;
        w1t[u] = (_Float16)W1[k * 128 + c];
    } else if (t < 128 * 96 + 32768) {        // W2T[c][k]
        int u = t - 128 * 96 - 16384; int c = u >> 7, k = u & 127;
        w2t[u] = (_Float16)W2[k * 128 + c];
    }
    if (t < 512) stats[t] = 0ULL;
    if (t < 8) prog[t * 64] = 0;              // flags padded 256B apart
    if (t == 0) *cntT = 0;
}

// ---------------------------------------------------------------- front
// Blocks 0..7: r3-exact FPS loop (measured floor; r4/r5/r7 variants all
// regressed) + WAVE-0-ONLY index flush every 128 iters: 128 packed int
// stores + release prog — NO block barrier (r12: the old __syncthreads put
// the agent-store drain on all 4 waves' critical path; wave 0's vmcnt
// stall now overlaps the next iteration's distance update). sSeq[<=i] is
// ordered by the per-iteration barrier; stores+release are wave-0 program
// order -> acquire/release pairing is sufficient. prog flags padded 256B
// apart (were all in ONE cache line: 8 producers + 248 pollers contended).
// Blocks 8..255: per-query consumers — spin (s_sleep) on prog, read idx,
// reconstruct centroid from pos[b,idx] (immutable input -> bit-identical),
// nbr exact-rank-select + gather + GEMM0 + stats0 (r8 col-sliced).
template<int CTRL>
__device__ inline unsigned long long dpp64(unsigned long long v) {
    int lo = (int)(unsigned)v, hi = (int)(unsigned)(v >> 32);
    int nlo = __builtin_amdgcn_update_dpp(lo, lo, CTRL, 0xF, 0xF, false);
    int nhi = __builtin_amdgcn_update_dpp(hi, hi, CTRL, 0xF, 0xF, false);
    return ((unsigned long long)(unsigned)nhi << 32) | (unsigned long long)(unsigned)nlo;
}
__device__ inline unsigned long long u64max(unsigned long long a, unsigned long long b) {
    return (b > a) ? b : a;
}

__global__ __launch_bounds__(256) void k_front(const float* __restrict__ pos,
        const float* __restrict__ x, const _Float16* __restrict__ w0t,
        const float* __restrict__ b0, float* __restrict__ outCtr, float* __restrict__ outBatch,
        unsigned short* __restrict__ nbrG, int* __restrict__ cnt, int* __restrict__ cntT,
        unsigned long long* __restrict__ statsOut, int* prog, int* idxG) {
    __shared__ __align__(16) char uLDS[84480];   // >81920 -> 1 block/CU
    int tid = threadIdx.x;

    if (blockIdx.x < 8) {
        // ================= PRODUCER =================
        float4* sP4 = (float4*)uLDS;                               // 64 KB
        unsigned long long* red = (unsigned long long*)(uLDS + 65536);
        unsigned short* sSeq = (unsigned short*)(uLDS + 65600);    // 4 KB
        int b = blockIdx.x;
        const float* P = pos + (size_t)b * N_ * 3;

        float px[16], py[16], pz[16], md[16];
        {
            const float4* vp = (const float4*)(P + tid * 48);
            float a[48];
            #pragma unroll
            for (int v = 0; v < 12; v++) {
                float4 t4 = vp[v];
                a[v*4] = t4.x; a[v*4+1] = t4.y; a[v*4+2] = t4.z; a[v*4+3] = t4.w;
            }
            #pragma unroll
            for (int j = 0; j < 16; j++) {
                px[j] = a[3*j]; py[j] = a[3*j+1]; pz[j] = a[3*j+2];
                md[j] = __builtin_inff();
                sP4[tid * 16 + j] = make_float4(px[j], py[j], pz[j], 0.f);
            }
        }
        __syncthreads();

        int last = 0;
        for (int i = 0; i < S_; i++) {
            float4 cc = sP4[last];                       // broadcast ds_read_b128
            if (tid == (i & 255)) sSeq[i] = (unsigned short)last;
            unsigned long long best;
            {
                #pragma clang fp contract(off)
                float bv = -1.f; unsigned bi = 0;
                #pragma unroll
                for (int j = 0; j < 16; j++) {
                    float dx = px[j] - cc.x, dy = py[j] - cc.y, dz = pz[j] - cc.z;
                    float d = (dx * dx + dy * dy) + dz * dz;   // numpy order, no fma
                    float m = fminf(md[j], d); md[j] = m;
                    if (m > bv) { bv = m; bi = (unsigned)j; } // strict > => first index
                }
                best = ((unsigned long long)__float_as_uint(bv) << 32)
                     | (unsigned long long)(0xFFFFu - (unsigned)(tid * 16) - bi);
            }
            best = u64max(best, dpp64<0x111>(best));   // row_shr:1
            best = u64max(best, dpp64<0x112>(best));   // row_shr:2
            best = u64max(best, dpp64<0x114>(best));   // row_shr:4
            best = u64max(best, dpp64<0x118>(best));   // row_shr:8
            best = u64max(best, dpp64<0x142>(best));   // row_bcast:15
            best = u64max(best, dpp64<0x143>(best));   // row_bcast:31 -> lane63 = wave max
            if ((tid & 63) == 63) red[(i & 1) * 4 + (tid >> 6)] = best;
            __syncthreads();   // double-buffered red: one barrier/iter race-free
            ulonglong2 ra = *(const ulonglong2*)&red[(i & 1) * 4];
            ulonglong2 rb = *(const ulonglong2*)&red[(i & 1) * 4 + 2];
            unsigned long long g = u64max(u64max(ra.x, ra.y), u64max(rb.x, rb.y));
            last = (int)(0xFFFFu - (unsigned)(g & 0xFFFFu));
            if ((i & (FLUSH - 1)) == (FLUSH - 1)) {
                // wave-0-only flush: 128 idx stores + release. No block
                // barrier — wave 0's store-drain overlaps next iteration's
                // update on waves 1..3 (red is double-buffered).
                if (tid < 64) {
                    #pragma unroll
                    for (int u = 0; u < FLUSH / 64; u++) {
                        int ii = i - FLUSH + 1 + u * 64 + tid;
                        __hip_atomic_store(&idxG[b * S_ + ii], (int)sSeq[ii],
                                           __ATOMIC_RELAXED, __HIP_MEMORY_SCOPE_AGENT);
                    }
                }
                if (tid == 0)
                    __hip_atomic_store(&prog[b * 64], i + 1, __ATOMIC_RELEASE, __HIP_MEMORY_SCOPE_AGENT);
            }
        }
        __syncthreads();
        for (int i = tid; i < S_; i += 256) {    // bulk epilogue write (once)
            int o = b * S_ + i;
            float4 c = sP4[sSeq[i]];
            outCtr[o*3] = c.x; outCtr[o*3+1] = c.y; outCtr[o*3+2] = c.z;
            outBatch[o] = (float)b;
        }
    } else {
        // ================= CONSUMER =================
        float* cD = (float*)uLDS;                          // 4 KB
        unsigned short* cI = (unsigned short*)(uLDS + 4096);
        unsigned short* sNbr = (unsigned short*)(uLDS + 6144);
        float* sB0v = (float*)(uLDS + 6272);
        float* sCtr = (float*)(uLDS + 6784);
        int* cN = (int*)(uLDS + 6800);
        _Float16* sBuf = (_Float16*)(uLDS + 6912);         // 64*104 f16

        int wid = tid >> 6, lane = tid & 63;
        int lr = lane & 15, lq = lane >> 4;
        int colbase = 32 * wid + lr;
        half8 w0f[3][2];
        #pragma unroll
        for (int ks = 0; ks < 3; ks++)
            #pragma unroll
            for (int nt = 0; nt < 2; nt++)
                w0f[ks][nt] = *(const half8*)(w0t + (colbase + 16*nt) * 96 + ks * 32 + lq * 8);
        if (tid < 128) sB0v[tid] = b0[tid];
        float runS1[2] = {0.f, 0.f}, runS2[2] = {0.f, 0.f};

        for (int k = (int)blockIdx.x - 8; k < Q_; k += NCONS) {
            int i = k >> 3, b = k & 7;
            int q = (b << 11) + i;
            if (tid == 0) {
                while (__hip_atomic_load(&prog[b * 64], __ATOMIC_ACQUIRE, __HIP_MEMORY_SCOPE_AGENT) <= i)
                    __builtin_amdgcn_s_sleep(64);
                int idx = __hip_atomic_load(&idxG[b * S_ + i], __ATOMIC_RELAXED, __HIP_MEMORY_SCOPE_AGENT);
                const float* pc = pos + ((size_t)b * N_ + idx) * 3;   // immutable input:
                sCtr[0] = pc[0]; sCtr[1] = pc[1]; sCtr[2] = pc[2];    // bit-identical coords
                *cN = 0;
            }
            __syncthreads();   // B1
            float cx = sCtr[0], cy = sCtr[1], cz = sCtr[2];
            const float* P = pos + (size_t)b * N_ * 3;
            float a[48];
            {
                const float4* vp = (const float4*)(P + (size_t)tid * 48);
                #pragma unroll
                for (int v = 0; v < 12; v++) {
                    float4 t4 = vp[v];
                    a[v*4] = t4.x; a[v*4+1] = t4.y; a[v*4+2] = t4.z; a[v*4+3] = t4.w;
                }
            }
            unsigned msk = 0;
            float d2a[16];
            {
                #pragma clang fp contract(off)
                #pragma unroll
                for (int j = 0; j < 16; j++) {
                    float dx = cx - a[3*j], dy = cy - a[3*j+1], dz = cz - a[3*j+2];
                    float d2 = (dx * dx + dy * dy) + dz * dz;
                    d2a[j] = d2;
                    if (d2 <= 0.04f) msk |= 1u << j;     // f32(0.2**2) boundary, exact
                }
            }
            int myc = __popc(msk);
            int base = 0;
            if (myc) base = atomicAdd(cN, myc);          // one atomic per hitting thread
            unsigned mm = msk;
            while (mm) {
                int j = __builtin_ctz(mm); mm &= mm - 1;
                if (base < 1024) { cD[base] = d2a[j]; cI[base] = (unsigned short)(tid * 16 + j); }
                base++;
            }
            __syncthreads();   // B2
            int M = min(*cN, 1024);
            int n = min(M, K_);
            for (int i2 = tid; i2 < M; i2 += 256) {
                float di = cD[i2]; int ii = (int)cI[i2]; int r = 0;
                for (int j = 0; j < M; j++) {
                    float dj = cD[j];
                    r += (dj < di) || (dj == di && (int)cI[j] < ii);   // stable tie-break
                }
                if (r < K_) { nbrG[q * K_ + r] = (unsigned short)ii; sNbr[r] = (unsigned short)ii; }
            }
            if (tid == 0) { cnt[q] = n; atomicAdd(cntT, n); }
            __syncthreads();   // B3
            {   // gather x_j -> feat cols 0..63 (f16), zero rows >= n
                int row = tid >> 2, c4 = (tid & 3) * 16;
                half8 o0, o1;
                #pragma unroll
                for (int e = 0; e < 8; e++) { o0[e] = (_Float16)0.f; o1[e] = (_Float16)0.f; }
                if (row < n) {
                    const float4* xr = (const float4*)(x + ((size_t)b * N_ + sNbr[row]) * CIN + c4);
                    float4 v0 = xr[0], v1 = xr[1], v2 = xr[2], v3 = xr[3];
                    o0[0]=(_Float16)v0.x; o0[1]=(_Float16)v0.y; o0[2]=(_Float16)v0.z; o0[3]=(_Float16)v0.w;
                    o0[4]=(_Float16)v1.x; o0[5]=(_Float16)v1.y; o0[6]=(_Float16)v1.z; o0[7]=(_Float16)v1.w;
                    o1[0]=(_Float16)v2.x; o1[1]=(_Float16)v2.y; o1[2]=(_Float16)v2.z; o1[3]=(_Float16)v2.w;
                    o1[4]=(_Float16)v3.x; o1[5]=(_Float16)v3.y; o1[6]=(_Float16)v3.z; o1[7]=(_Float16)v3.w;
                }
                *(half8*)&sBuf[row * 104 + c4]     = o0;
                *(half8*)&sBuf[row * 104 + c4 + 8] = o1;
            }
            if (tid < 64) {   // cols 64..66 = pos_j - ctr, 67..95 = 0
                half8 z, o;
                #pragma unroll
                for (int e = 0; e < 8; e++) { z[e] = (_Float16)0.f; o[e] = (_Float16)0.f; }
                if (tid < n) {
                    int j = sNbr[tid];
                    const float* pj = pos + ((size_t)b * N_ + j) * 3;
                    o[0] = (_Float16)(pj[0] - cx); o[1] = (_Float16)(pj[1] - cy); o[2] = (_Float16)(pj[2] - cz);
                }
                *(half8*)&sBuf[tid * 104 + 64] = o;
                *(half8*)&sBuf[tid * 104 + 72] = z;
                *(half8*)&sBuf[tid * 104 + 80] = z;
                *(half8*)&sBuf[tid * 104 + 88] = z;
            }
            __syncthreads();   // B4
            floatx4 acc[4][2];
            #pragma unroll
            for (int rt = 0; rt < 4; rt++)
                #pragma unroll
                for (int nt = 0; nt < 2; nt++)
                    #pragma unroll
                    for (int r = 0; r < 4; r++) acc[rt][nt][r] = 0.f;
            #pragma unroll
            for (int ks = 0; ks < 3; ks++) {
                half8 av[4];
                #pragma unroll
                for (int rt = 0; rt < 4; rt++)
                    av[rt] = *(const half8*)&sBuf[(rt * 16 + lr) * 104 + ks * 32 + lq * 8];
                #pragma unroll
                for (int rt = 0; rt < 4; rt++)
                    #pragma unroll
                    for (int nt = 0; nt < 2; nt++)
                        acc[rt][nt] = __builtin_amdgcn_mfma_f32_16x16x32_f16(av[rt], w0f[ks][nt], acc[rt][nt], 0, 0, 0);
            }
            #pragma unroll
            for (int nt = 0; nt < 2; nt++) {
                int col = colbase + 16 * nt;
                float bias = sB0v[col];
                #pragma unroll
                for (int rt = 0; rt < 4; rt++) {
                    int r0 = rt * 16 + lq * 4;
                    #pragma unroll
                    for (int r = 0; r < 4; r++) {
                        float v = acc[rt][nt][r] + bias;
                        if (r0 + r < n) { runS1[nt] += v; runS2[nt] += v * v; }
                    }
                }
            }
        }
        #pragma unroll
        for (int nt = 0; nt < 2; nt++) {
            float s1 = runS1[nt], s2 = runS2[nt];
            s1 += __shfl_xor(s1, 16); s1 += __shfl_xor(s1, 32);
            s2 += __shfl_xor(s2, 16); s2 += __shfl_xor(s2, 32);
            if (lq == 0) {   // fixed-point (2^20) i64 atomics: deterministic
                int col = colbase + 16 * nt;
                atomicAdd(&statsOut[col],       (unsigned long long)(long long)llrintf(s1 * 1048576.f));
                atomicAdd(&statsOut[128 + col], (unsigned long long)(long long)llrintf(s2 * 1048576.f));
            }
        }
    }
}

// ---------------------------------------------------------------- tail MLP (r8 col-sliced, recompute)
// BN params computed INLINE per block from the deterministic fixed-point
// stats (identical doubles in every block).
template<int STAGE>
__global__ __launch_bounds__(256, 3) void k_mlp(const float* __restrict__ x,
        const float* __restrict__ pos, const float* __restrict__ ctr,
        const unsigned short* __restrict__ nbr, const int* __restrict__ cnt,
        const _Float16* __restrict__ w0t, const _Float16* __restrict__ w1t,
        const _Float16* __restrict__ w2t,
        const float* __restrict__ b0, const float* __restrict__ b1,
        const float* __restrict__ b2,
        const float* __restrict__ g0, const float* __restrict__ be0,
        const float* __restrict__ g1, const float* __restrict__ be1,
        const int* __restrict__ cntT,
        const unsigned long long* __restrict__ stats0,
        const unsigned long long* __restrict__ stats1,
        unsigned long long* __restrict__ statsOut, float* __restrict__ outF) {
    __shared__ __align__(16) _Float16 sBuf[64 * 136];   // feat(104) / h'(136)
    __shared__ unsigned short sNbr[64];
    __shared__ float sB0v[128];
    __shared__ float sB1v[128];
    __shared__ float sSc0[128];
    __shared__ float sSh0[128];
    __shared__ float sB2v[(STAGE >= 2) ? 128 : 4];
    __shared__ float sSc1[(STAGE >= 2) ? 128 : 4];
    __shared__ float sSh1[(STAGE >= 2) ? 128 : 4];

    int tid = threadIdx.x, wid = tid >> 6, lane = tid & 63;
    int lr = lane & 15, lq = lane >> 4;
    int colbase = 32 * wid + lr;

    if (tid < 128) {   // inline BN params (deterministic across blocks)
        double c = (double)(*cntT);
        double mean = (double)(long long)stats0[tid] * (1.0 / 1048576.0) / c;
        double ex2  = (double)(long long)stats0[128 + tid] * (1.0 / 1048576.0) / c;
        double var = ex2 - mean * mean;
        if (var < 0.0) var = 0.0;
        double sc = (double)g0[tid] / sqrt(var + 1e-5);
        sSc0[tid] = (float)sc;
        sSh0[tid] = (float)((double)be0[tid] - mean * sc);
        sB0v[tid] = b0[tid];
        sB1v[tid] = b1[tid];
        if constexpr (STAGE >= 2) {
            double mean1 = (double)(long long)stats1[tid] * (1.0 / 1048576.0) / c;
            double ex21  = (double)(long long)stats1[128 + tid] * (1.0 / 1048576.0) / c;
            double var1 = ex21 - mean1 * mean1;
            if (var1 < 0.0) var1 = 0.0;
            double sc1 = (double)g1[tid] / sqrt(var1 + 1e-5);
            sSc1[tid] = (float)sc1;
            sSh1[tid] = (float)((double)be1[tid] - mean1 * sc1);
            sB2v[tid] = b2[tid];
        }
    }

    half8 w0f[3][2];
    #pragma unroll
    for (int ks = 0; ks < 3; ks++)
        #pragma unroll
        for (int nt = 0; nt < 2; nt++)
            w0f[ks][nt] = *(const half8*)(w0t + (colbase + 16*nt) * 96 + ks * 32 + lq * 8);
    half8 w1f[4][2];
    #pragma unroll
    for (int ks = 0; ks < 4; ks++)
        #pragma unroll
        for (int nt = 0; nt < 2; nt++)
            w1f[ks][nt] = *(const half8*)(w1t + (colbase + 16*nt) * 128 + ks * 32 + lq * 8);
    half8 w2f[(STAGE >= 2) ? 4 : 1][2];
    if constexpr (STAGE >= 2)
        #pragma unroll
        for (int ks = 0; ks < 4; ks++)
            #pragma unroll
            for (int nt = 0; nt < 2; nt++)
                w2f[ks][nt] = *(const half8*)(w2t + (colbase + 16*nt) * 128 + ks * 32 + lq * 8);

    float runS1[2] = {0.f, 0.f}, runS2[2] = {0.f, 0.f};

    for (int qq = 0; qq < 8; qq++) {
        int q = blockIdx.x * 8 + qq;
        int b = q >> 11;
        __syncthreads();                    // prior-iter readers done; BN params visible
        int n = cnt[q];
        if (tid < 64) sNbr[tid] = nbr[q * K_ + tid];
        __syncthreads();
        {   // gather x_j -> feat cols 0..63 (f16), zero rows >= n
            int row = tid >> 2, c4 = (tid & 3) * 16;
            half8 o0, o1;
            #pragma unroll
            for (int e = 0; e < 8; e++) { o0[e] = (_Float16)0.f; o1[e] = (_Float16)0.f; }
            if (row < n) {
                const float4* xr = (const float4*)(x + ((size_t)b * N_ + sNbr[row]) * CIN + c4);
                float4 v0 = xr[0], v1 = xr[1], v2 = xr[2], v3 = xr[3];
                o0[0]=(_Float16)v0.x; o0[1]=(_Float16)v0.y; o0[2]=(_Float16)v0.z; o0[3]=(_Float16)v0.w;
                o0[4]=(_Float16)v1.x; o0[5]=(_Float16)v1.y; o0[6]=(_Float16)v1.z; o0[7]=(_Float16)v1.w;
                o1[0]=(_Float16)v2.x; o1[1]=(_Float16)v2.y; o1[2]=(_Float16)v2.z; o1[3]=(_Float16)v2.w;
                o1[4]=(_Float16)v3.x; o1[5]=(_Float16)v3.y; o1[6]=(_Float16)v3.z; o1[7]=(_Float16)v3.w;
            }
            *(half8*)&sBuf[row * 104 + c4]     = o0;
            *(half8*)&sBuf[row * 104 + c4 + 8] = o1;
        }
        if (tid < 64) {
            half8 z, o;
            #pragma unroll
            for (int e = 0; e < 8; e++) { z[e] = (_Float16)0.f; o[e] = (_Float16)0.f; }
            if (tid < n) {
                int j = sNbr[tid];
                float cx = ctr[q*3], cy = ctr[q*3+1], cz = ctr[q*3+2];
                const float* pj = pos + ((size_t)b * N_ + j) * 3;
                o[0] = (_Float16)(pj[0] - cx); o[1] = (_Float16)(pj[1] - cy); o[2] = (_Float16)(pj[2] - cz);
            }
            *(half8*)&sBuf[tid * 104 + 64] = o;
            *(half8*)&sBuf[tid * 104 + 72] = z;
            *(half8*)&sBuf[tid * 104 + 80] = z;
            *(half8*)&sBuf[tid * 104 + 88] = z;
        }
        __syncthreads();

        // ---- GEMM0: K=96
        floatx4 acc[4][2];
        #pragma unroll
        for (int rt = 0; rt < 4; rt++)
            #pragma unroll
            for (int nt = 0; nt < 2; nt++)
                #pragma unroll
                for (int r = 0; r < 4; r++) acc[rt][nt][r] = 0.f;
        #pragma unroll
        for (int ks = 0; ks < 3; ks++) {
            half8 av[4];
            #pragma unroll
            for (int rt = 0; rt < 4; rt++)
                av[rt] = *(const half8*)&sBuf[(rt * 16 + lr) * 104 + ks * 32 + lq * 8];
            #pragma unroll
            for (int rt = 0; rt < 4; rt++)
                #pragma unroll
                for (int nt = 0; nt < 2; nt++)
                    acc[rt][nt] = __builtin_amdgcn_mfma_f32_16x16x32_f16(av[rt], w0f[ks][nt], acc[rt][nt], 0, 0, 0);
        }
        __syncthreads();
        // BN0 + ReLU -> f16 A-matrix for GEMM1
        #pragma unroll
        for (int nt = 0; nt < 2; nt++) {
            int col = colbase + 16 * nt;
            float bias = sB0v[col], s = sSc0[col], t2 = sSh0[col];
            #pragma unroll
            for (int rt = 0; rt < 4; rt++) {
                int r0 = rt * 16 + lq * 4;
                #pragma unroll
                for (int r = 0; r < 4; r++) {
                    float v = (acc[rt][nt][r] + bias) * s + t2;
                    sBuf[(r0 + r) * 136 + col] = (_Float16)fmaxf(v, 0.f);
                }
            }
        }
        __syncthreads();
        // ---- GEMM1: K=128
        #pragma unroll
        for (int rt = 0; rt < 4; rt++)
            #pragma unroll
            for (int nt = 0; nt < 2; nt++)
                #pragma unroll
                for (int r = 0; r < 4; r++) acc[rt][nt][r] = 0.f;
        #pragma unroll
        for (int ks = 0; ks < 4; ks++) {
            half8 av[4];
            #pragma unroll
            for (int rt = 0; rt < 4; rt++)
                av[rt] = *(const half8*)&sBuf[(rt * 16 + lr) * 136 + ks * 32 + lq * 8];
            #pragma unroll
            for (int rt = 0; rt < 4; rt++)
                #pragma unroll
                for (int nt = 0; nt < 2; nt++)
                    acc[rt][nt] = __builtin_amdgcn_mfma_f32_16x16x32_f16(av[rt], w1f[ks][nt], acc[rt][nt], 0, 0, 0);
        }

        if constexpr (STAGE == 1) {
            #pragma unroll
            for (int nt = 0; nt < 2; nt++) {
                int col = colbase + 16 * nt;
                float bias = sB1v[col];
                #pragma unroll
                for (int rt = 0; rt < 4; rt++) {
                    int r0 = rt * 16 + lq * 4;
                    #pragma unroll
                    for (int r = 0; r < 4; r++) {
                        float v = acc[rt][nt][r] + bias;
                        if (r0 + r < n) { runS1[nt] += v; runS2[nt] += v * v; }
                    }
                }
            }
        } else {
            __syncthreads();            // GEMM1 A-reads done before overwrite
            // BN1 + ReLU -> f16 A-matrix for GEMM2
            #pragma unroll
            for (int nt = 0; nt < 2; nt++) {
                int col = colbase + 16 * nt;
                float bias = sB1v[col], s = sSc1[col], t2 = sSh1[col];
                #pragma unroll
                for (int rt = 0; rt < 4; rt++) {
                    int r0 = rt * 16 + lq * 4;
                    #pragma unroll
                    for (int r = 0; r < 4; r++) {
                        float v = (acc[rt][nt][r] + bias) * s + t2;
                        sBuf[(r0 + r) * 136 + col] = (_Float16)fmaxf(v, 0.f);
                    }
                }
            }
            __syncthreads();
            // ---- GEMM2: K=128
            #pragma unroll
            for (int rt = 0; rt < 4; rt++)
                #pragma unroll
                for (int nt = 0; nt < 2; nt++)
                    #pragma unroll
                    for (int r = 0; r < 4; r++) acc[rt][nt][r] = 0.f;
            #pragma unroll
            for (int ks = 0; ks < 4; ks++) {
                half8 av[4];
                #pragma unroll
                for (int rt = 0; rt < 4; rt++)
                    av[rt] = *(const half8*)&sBuf[(rt * 16 + lr) * 136 + ks * 32 + lq * 8];
                #pragma unroll
                for (int rt = 0; rt < 4; rt++)
                    #pragma unroll
                    for (int nt = 0; nt < 2; nt++)
                        acc[rt][nt] = __builtin_amdgcn_mfma_f32_16x16x32_f16(av[rt], w2f[ks][nt], acc[rt][nt], 0, 0, 0);
            }
            // masked max over all rows (wave owns its cols) -> direct store
            #pragma unroll
            for (int nt = 0; nt < 2; nt++) {
                int col = colbase + 16 * nt;
                float bias = sB2v[col];
                float m = -__builtin_inff();
                #pragma unroll
                for (int rt = 0; rt < 4; rt++) {
                    int r0 = rt * 16 + lq * 4;
                    #pragma unroll
                    for (int r = 0; r < 4; r++)
                        if (r0 + r < n) m = fmaxf(m, acc[rt][nt][r] + bias);
                }
                m = fmaxf(m, __shfl_xor(m, 16));
                m = fmaxf(m, __shfl_xor(m, 32));
                if (lq == 0) outF[(size_t)q * 128 + col] = m;
            }
        }
    }
    if constexpr (STAGE == 1) {
        #pragma unroll
        for (int nt = 0; nt < 2; nt++) {
            float s1 = runS1[nt], s2 = runS2[nt];
            s1 += __shfl_xor(s1, 16); s1 += __shfl_xor(s1, 32);
            s2 += __shfl_xor(s2, 16); s2 += __shfl_xor(s2, 32);
            if (lq == 0) {
                int col = colbase + 16 * nt;
                atomicAdd(&statsOut[col],       (unsigned long long)(long long)llrintf(s1 * 1048576.f));
                atomicAdd(&statsOut[128 + col], (unsigned long long)(long long)llrintf(s2 * 1048576.f));
            }
        }
    }
}

// ---------------------------------------------------------------- launch
extern "C" void kernel_launch(void* const* d_in, const int* in_sizes, int n_in,
                              void* d_out, int out_size, void* d_ws, size_t ws_size,
                              hipStream_t stream) {
    const float* x   = (const float*)d_in[0];
    const float* pos = (const float*)d_in[1];
    const float* W0  = (const float*)d_in[3];
    const float* b0  = (const float*)d_in[4];
    const float* g0  = (const float*)d_in[5];
    const float* be0 = (const float*)d_in[6];
    const float* W1  = (const float*)d_in[7];
    const float* b1  = (const float*)d_in[8];
    const float* g1  = (const float*)d_in[9];
    const float* be1 = (const float*)d_in[10];
    const float* W2  = (const float*)d_in[11];
    const float* b2  = (const float*)d_in[12];

    char* ws = (char*)d_ws;
    unsigned long long* stats = (unsigned long long*)(ws + WS_STATS);
    int* cntT = (int*)(ws + WS_CNTT);
    _Float16* w0t = (_Float16*)(ws + WS_W0T);
    _Float16* w1t = (_Float16*)(ws + WS_W1T);
    _Float16* w2t = (_Float16*)(ws + WS_W2T);
    int* cnt = (int*)(ws + WS_CNT);
    unsigned short* nbr = (unsigned short*)(ws + WS_NBR);
    int* prog = (int*)(ws + WS_PROG);
    int* idxG = (int*)(ws + WS_IDX);

    float* outF = (float*)d_out;                  // [16384,128]
    float* outCtr = (float*)d_out + 2097152;      // [16384,3]
    float* outBatch = (float*)d_out + 2146304;    // [16384]

    k_prep<<<176, 256, 0, stream>>>(W0, W1, W2, w0t, w1t, w2t, stats, cntT, prog);
    k_front<<<256, 256, 0, stream>>>(pos, x, w0t, b0, outCtr, outBatch, nbr, cnt, cntT,
            stats, prog, idxG);
    k_mlp<1><<<Q_/8, 256, 0, stream>>>(x, pos, outCtr, nbr, cnt, w0t, w1t, w2t,
            b0, b1, b2, g0, be0, g1, be1, cntT, stats, stats + 256, stats + 256, outF);
    k_mlp<2><<<Q_/8, 256, 0, stream>>>(x, pos, outCtr, nbr, cnt, w0t, w1t, w2t,
            b0, b1, b2, g0, be0, g1, be1, cntT, stats, stats + 256, stats, outF);
}